// Round 4
// baseline (380.013 us; speedup 1.0000x reference)
//
#include <hip/hip_runtime.h>
#include <hip/hip_bf16.h>

#define NN 100000
#define EE 400000
#define STRIPS 6250          // NN/16, exact

typedef unsigned short u16;
typedef unsigned int u32;
typedef __attribute__((ext_vector_type(4))) float floatx4;
typedef __attribute__((ext_vector_type(8))) short shortx8;
typedef __attribute__((ext_vector_type(4))) unsigned short ushortx4;

__device__ __forceinline__ u16 f2bf(float f) {
    unsigned u = __float_as_uint(f);
    u += 0x7FFFu + ((u >> 16) & 1u);
    return (u16)(u >> 16);
}

// ---- mark degree masks: idempotent byte stores (atomics were 4x slower:
// 1.2M contended RMWs serialize; plain stores just migrate L2 lines).
// int4-vectorized edge reads -> 12 independent stores per thread.
__global__ __launch_bounds__(256) void mark(
    const int4* __restrict__ daa, const int4* __restrict__ dab,
    const int4* __restrict__ dba, unsigned char* __restrict__ m) {
    int i = blockIdx.x * 256 + threadIdx.x;
    if (i < EE / 4) {
        int4 a = daa[i], b = dab[i], c = dba[i];
        m[a.x] = 1; m[a.y] = 1; m[a.z] = 1; m[a.w] = 1;
        m[NN + b.x] = 1; m[NN + b.y] = 1; m[NN + b.z] = 1; m[NN + b.w] = 1;
        m[2 * NN + c.x] = 1; m[2 * NN + c.y] = 1; m[2 * NN + c.z] = 1; m[2 * NN + c.w] = 1;
    }
}

// ---- persistent fused 2-layer kernel.
// out[m] = relu(s^2*(z@W1) + s*b1), z = relu(feat@W0 + b0)   [relu(s*x)=s*relu(x), s>0]
// Transposed MFMA form D = W^T x feat^T (R3-verified layouts). W0/W1 converted
// fp32->bf16 frag-order into LDS once per block; waves then steal 16-row strips
// from a global counter with NO barriers (h1 hand-off via wave-private LDS).
__global__ __launch_bounds__(1024, 4) void fused2(
    const float* __restrict__ featA, const float* __restrict__ featB,
    const float* __restrict__ Wr0, const float* __restrict__ Wr1,
    const float* __restrict__ br0, const float* __restrict__ br1,
    const unsigned char* __restrict__ masks, u32* __restrict__ counters,
    float* __restrict__ out) {
    __shared__ u16 lds[65536];   // [W0f 16384][W1f 16384][h1: 16 waves x 2048]

    const int type = blockIdx.x >> 7;          // 128 blocks per type
    const float* feat = type ? featB : featA;
    const float* W0 = Wr0 + type * 16384;
    const float* W1 = Wr1 + type * 16384;
    const float* b0 = br0 + type * 128;
    const float* b1 = br1 + type * 128;
    float* outp = out + (size_t)type * NN * 128;

    const int t = threadIdx.x;
    // stage+convert both W matrices into MFMA A-frag order (coalesced reads)
#pragma unroll
    for (int i = 0; i < 32; ++i) {
        int e = i * 1024 + t;                  // [0, 32768)
        int mat = e >> 14;
        int k = (e >> 7) & 127;
        int n = e & 127;
        float v = (mat ? W1 : W0)[k * 128 + n];
        int chunk = (k >> 5) * 8 + (n >> 4);
        int lane2 = ((k >> 3) & 3) * 16 + (n & 15);
        lds[mat * 16384 + chunk * 512 + lane2 * 8 + (k & 7)] = f2bf(v);
    }
    __syncthreads();   // the only barrier

    const int wave = t >> 6, lane = t & 63;
    const int quad = lane >> 4, mrow = lane & 15;
    const int h1base = 32768 + wave * 2048;
    u32* counter = counters + type;

    for (;;) {
        int strip = 0;
        if (lane == 0) strip = (int)atomicAdd(counter, 1u);
        strip = __shfl(strip, 0);
        if (strip >= STRIPS) break;

        const int m0 = strip * 16;
        const int row = m0 + mrow;             // always < NN (NN % 16 == 0)

        // per-row scale (used only in final epilogue; issue loads early)
        float s;
        if (type) s = (1.0f + (float)masks[NN + row]) * 0.5f;
        else      s = (1.0f + (float)masks[row] + (float)masks[2 * NN + row]) * (1.0f / 3.0f);
        const float s2 = s * s;

        // feat B-frags: B[k = ks*32+quad*8+j][m = row]
        shortx8 bfrag[4];
        {
            const float* arow = feat + (size_t)row * 128;
#pragma unroll
            for (int ks = 0; ks < 4; ++ks) {
                floatx4 f0 = *(const floatx4*)(arow + ks * 32 + quad * 8);
                floatx4 f1 = *(const floatx4*)(arow + ks * 32 + quad * 8 + 4);
                union { shortx8 v; u16 u[8]; } uu;
                uu.u[0] = f2bf(f0[0]); uu.u[1] = f2bf(f0[1]);
                uu.u[2] = f2bf(f0[2]); uu.u[3] = f2bf(f0[3]);
                uu.u[4] = f2bf(f1[0]); uu.u[5] = f2bf(f1[1]);
                uu.u[6] = f2bf(f1[2]); uu.u[7] = f2bf(f1[3]);
                bfrag[ks] = uu.v;
            }
        }

        // GEMM1: acc[nt] = W0^T tile(nt) x feat^T
        floatx4 acc[8];
#pragma unroll
        for (int nt = 0; nt < 8; ++nt) acc[nt] = (floatx4){0.f, 0.f, 0.f, 0.f};
#pragma unroll
        for (int ks = 0; ks < 4; ++ks)
#pragma unroll
            for (int nt = 0; nt < 8; ++nt) {
                shortx8 af = *(const shortx8*)&lds[((ks * 8 + nt) << 9) + lane * 8];
                acc[nt] = __builtin_amdgcn_mfma_f32_16x16x32_bf16(af, bfrag[ks], acc[nt], 0, 0, 0);
            }

        // epilogue1: z = relu(acc + b0)  (NO scale), write wave-private h1 in
        // GEMM2 B-frag order (index algebra verified in R3)
#pragma unroll
        for (int nt = 0; nt < 8; ++nt) {
            floatx4 bv = *(const floatx4*)(b0 + nt * 16 + quad * 4);
            ushortx4 p;
#pragma unroll
            for (int r = 0; r < 4; ++r)
                p[r] = f2bf(fmaxf(acc[nt][r] + bv[r], 0.0f));
            int q2 = (2 * nt + (quad >> 1)) & 3;
            *(ushortx4*)&lds[h1base + (nt >> 1) * 512 + q2 * 128 + mrow * 8 + (quad & 1) * 4] = p;
        }

        shortx8 h1b[4];
#pragma unroll
        for (int ks = 0; ks < 4; ++ks)
            h1b[ks] = *(const shortx8*)&lds[h1base + ks * 512 + lane * 8];

        // GEMM2: acc2[nt] = W1^T tile(nt) x z^T
        floatx4 acc2[8];
#pragma unroll
        for (int nt = 0; nt < 8; ++nt) acc2[nt] = (floatx4){0.f, 0.f, 0.f, 0.f};
#pragma unroll
        for (int ks = 0; ks < 4; ++ks)
#pragma unroll
            for (int nt = 0; nt < 8; ++nt) {
                shortx8 af = *(const shortx8*)&lds[16384 + ((ks * 8 + nt) << 9) + lane * 8];
                acc2[nt] = __builtin_amdgcn_mfma_f32_16x16x32_bf16(af, h1b[ks], acc2[nt], 0, 0, 0);
            }

        // epilogue2: out = relu(s^2*acc2 + s*b1), 8 x float4 per lane
        float* orow = outp + (size_t)row * 128;
#pragma unroll
        for (int nt = 0; nt < 8; ++nt) {
            floatx4 bv = *(const floatx4*)(b1 + nt * 16 + quad * 4);
            floatx4 o;
#pragma unroll
            for (int r = 0; r < 4; ++r)
                o[r] = fmaxf(s2 * acc2[nt][r] + s * bv[r], 0.0f);
            *(floatx4*)(orow + nt * 16 + quad * 4) = o;
        }
    }
}

extern "C" void kernel_launch(void* const* d_in, const int* in_sizes, int n_in,
                              void* d_out, int out_size, void* d_ws, size_t ws_size,
                              hipStream_t stream) {
    (void)in_sizes; (void)n_in; (void)out_size; (void)ws_size;
    const float* featA = (const float*)d_in[0];
    const float* featB = (const float*)d_in[1];
    const int* dst_aa = (const int*)d_in[3];
    const int* dst_ab = (const int*)d_in[5];
    const int* dst_ba = (const int*)d_in[7];
    const float* Wr0 = (const float*)d_in[10];
    const float* br0 = (const float*)d_in[11];
    const float* Wr1 = (const float*)d_in[16];
    const float* br1 = (const float*)d_in[17];

    char* ws = (char*)d_ws;
    u32* counters = (u32*)ws;                       // 2 x u32
    unsigned char* masks = (unsigned char*)(ws + 8);  // 3 x NN bytes

    hipMemsetAsync(ws, 0, 8 + (size_t)3 * NN, stream);
    mark<<<(EE / 4 + 255) / 256, 256, 0, stream>>>(
        (const int4*)dst_aa, (const int4*)dst_ab, (const int4*)dst_ba, masks);
    fused2<<<256, 1024, 0, stream>>>(featA, featB, Wr0, Wr1, br0, br1,
                                     masks, counters, (float*)d_out);
}

// Round 5
// 235.799 us; speedup vs baseline: 1.6116x; 1.6116x over previous
//
#include <hip/hip_runtime.h>
#include <hip/hip_bf16.h>

#define NN 100000
#define EE 400000
#define STRIPS 6250          // NN/16, exact
#define WAVES_TOT 1024       // 256 blocks/type * 4 waves

typedef unsigned short u16;
typedef __attribute__((ext_vector_type(4))) float floatx4;
typedef __attribute__((ext_vector_type(8))) short shortx8;
typedef __attribute__((ext_vector_type(4))) unsigned short ushortx4;
typedef __attribute__((ext_vector_type(8))) unsigned short ushortx8;

__device__ __forceinline__ u16 f2bf(float f) {
    unsigned u = __float_as_uint(f);
    u += 0x7FFFu + ((u >> 16) & 1u);
    return (u16)(u >> 16);
}

// ---- degree masks: idempotent byte stores, int4-vectorized edge reads
__global__ __launch_bounds__(256) void mark(
    const int4* __restrict__ daa, const int4* __restrict__ dab,
    const int4* __restrict__ dba, unsigned char* __restrict__ m) {
    int i = blockIdx.x * 256 + threadIdx.x;
    if (i < EE / 4) {
        int4 a = daa[i], b = dab[i], c = dba[i];
        m[a.x] = 1; m[a.y] = 1; m[a.z] = 1; m[a.w] = 1;
        m[NN + b.x] = 1; m[NN + b.y] = 1; m[NN + b.z] = 1; m[NN + b.w] = 1;
        m[2 * NN + c.x] = 1; m[2 * NN + c.y] = 1; m[2 * NN + c.z] = 1; m[2 * NN + c.w] = 1;
    }
}

// ---- persistent fused 2-layer, STATIC strip assignment + software pipeline.
// out[m] = relu(s^2*(z@W1) + s*b1), z = relu(feat@W0 + b0)   [relu(s*x)=s*relu(x)]
// Transposed MFMA form D = W^T x feat^T (layouts HW-verified R3/R4).
// 256 thr (4 waves), 80 KB LDS -> exactly 2 blocks/CU. Wave gw handles strips
// gw, gw+1024, ... ; next strip's feat row is prefetched into VGPRs before
// computing the current one (first prefetch overlaps W staging).
__global__ __launch_bounds__(256, 2) void fused2(
    const float* __restrict__ featA, const float* __restrict__ featB,
    const float* __restrict__ Wr0, const float* __restrict__ Wr1,
    const float* __restrict__ br0, const float* __restrict__ br1,
    const unsigned char* __restrict__ masks, float* __restrict__ out) {
    __shared__ u16 lds[40960];   // [W0f 16384][W1f 16384][h1: 4 waves x 2048]

    const int type = blockIdx.x >> 8;           // 256 blocks per type
    const int bid = blockIdx.x & 255;
    const float* feat = type ? featB : featA;
    const float* W0 = Wr0 + type * 16384;
    const float* W1 = Wr1 + type * 16384;
    const float* b0 = br0 + type * 128;
    const float* b1 = br1 + type * 128;
    float* outp = out + (size_t)type * NN * 128;

    const int t = threadIdx.x;
    const int wave = t >> 6, lane = t & 63;
    const int quad = lane >> 4, mrow = lane & 15;
    const int gw = bid * 4 + wave;              // [0, 1024)

    // ---- prefetch strip 0 of this wave (issued BEFORE staging barrier)
    int s = gw;
    floatx4 pf[8];
    unsigned char pm0 = 0, pm1 = 0;
    {
        const float* arow = feat + (size_t)(s * 16 + mrow) * 128;
#pragma unroll
        for (int ks = 0; ks < 4; ++ks) {
            pf[2 * ks]     = *(const floatx4*)(arow + ks * 32 + quad * 8);
            pf[2 * ks + 1] = *(const floatx4*)(arow + ks * 32 + quad * 8 + 4);
        }
        int row = s * 16 + mrow;
        if (type) pm0 = masks[NN + row];
        else { pm0 = masks[row]; pm1 = masks[2 * NN + row]; }
    }

    // ---- stage W0,W1 -> bf16 MFMA A-frag order (ds_write_b128, once/block)
#pragma unroll
    for (int i = 0; i < 16; ++i) {
        int g = i * 256 + t;                    // [0, 4096)
        int mat = g >> 11;
        int gg = g & 2047;
        int chunk = gg >> 6;                    // ks*8 + nt
        int l2 = gg & 63;
        int kbase = (chunk >> 3) * 32 + (l2 >> 4) * 8;
        int n = (chunk & 7) * 16 + (l2 & 15);
        const float* W = mat ? W1 : W0;
        ushortx8 p;
#pragma unroll
        for (int j = 0; j < 8; ++j) p[j] = f2bf(W[(kbase + j) * 128 + n]);
        *(ushortx8*)&lds[mat * 16384 + chunk * 512 + l2 * 8] = p;
    }
    __syncthreads();   // the only barrier

    const int h1base = 32768 + wave * 2048;

    for (;;) {
        // consume prefetch: bf16 B-frags + scale (before overwriting pf)
        shortx8 bfrag[4];
#pragma unroll
        for (int ks = 0; ks < 4; ++ks) {
            floatx4 f0 = pf[2 * ks], f1 = pf[2 * ks + 1];
            union { shortx8 v; u16 u[8]; } uu;
            uu.u[0] = f2bf(f0[0]); uu.u[1] = f2bf(f0[1]);
            uu.u[2] = f2bf(f0[2]); uu.u[3] = f2bf(f0[3]);
            uu.u[4] = f2bf(f1[0]); uu.u[5] = f2bf(f1[1]);
            uu.u[6] = f2bf(f1[2]); uu.u[7] = f2bf(f1[3]);
            bfrag[ks] = uu.v;
        }
        const float scl = type ? (1.0f + (float)pm0) * 0.5f
                               : (1.0f + (float)pm0 + (float)pm1) * (1.0f / 3.0f);
        const float s2 = scl * scl;
        const int row = s * 16 + mrow;

        // issue next strip's prefetch NOW (hidden under both GEMMs)
        const int sn = s + WAVES_TOT;
        const bool more = sn < STRIPS;
        if (more) {
            const float* arow = feat + (size_t)(sn * 16 + mrow) * 128;
#pragma unroll
            for (int ks = 0; ks < 4; ++ks) {
                pf[2 * ks]     = *(const floatx4*)(arow + ks * 32 + quad * 8);
                pf[2 * ks + 1] = *(const floatx4*)(arow + ks * 32 + quad * 8 + 4);
            }
            int nrow = sn * 16 + mrow;
            if (type) pm0 = masks[NN + nrow];
            else { pm0 = masks[nrow]; pm1 = masks[2 * NN + nrow]; }
        }

        // GEMM1: acc[nt] = W0^T tile(nt) x feat^T
        floatx4 acc[8];
#pragma unroll
        for (int nt = 0; nt < 8; ++nt) acc[nt] = (floatx4){0.f, 0.f, 0.f, 0.f};
#pragma unroll
        for (int ks = 0; ks < 4; ++ks)
#pragma unroll
            for (int nt = 0; nt < 8; ++nt) {
                shortx8 af = *(const shortx8*)&lds[((ks * 8 + nt) << 9) + lane * 8];
                acc[nt] = __builtin_amdgcn_mfma_f32_16x16x32_bf16(af, bfrag[ks], acc[nt], 0, 0, 0);
            }

        // epilogue1: z = relu(acc + b0), wave-private h1 in GEMM2 B-frag order
#pragma unroll
        for (int nt = 0; nt < 8; ++nt) {
            floatx4 bv = *(const floatx4*)(b0 + nt * 16 + quad * 4);
            ushortx4 p;
#pragma unroll
            for (int r = 0; r < 4; ++r)
                p[r] = f2bf(fmaxf(acc[nt][r] + bv[r], 0.0f));
            int q2 = (2 * nt + (quad >> 1)) & 3;
            *(ushortx4*)&lds[h1base + (nt >> 1) * 512 + q2 * 128 + mrow * 8 + (quad & 1) * 4] = p;
        }

        shortx8 h1b[4];
#pragma unroll
        for (int ks = 0; ks < 4; ++ks)
            h1b[ks] = *(const shortx8*)&lds[h1base + ks * 512 + lane * 8];

        // GEMM2: acc2[nt] = W1^T tile(nt) x z^T
        floatx4 acc2[8];
#pragma unroll
        for (int nt = 0; nt < 8; ++nt) acc2[nt] = (floatx4){0.f, 0.f, 0.f, 0.f};
#pragma unroll
        for (int ks = 0; ks < 4; ++ks)
#pragma unroll
            for (int nt = 0; nt < 8; ++nt) {
                shortx8 af = *(const shortx8*)&lds[16384 + ((ks * 8 + nt) << 9) + lane * 8];
                acc2[nt] = __builtin_amdgcn_mfma_f32_16x16x32_bf16(af, h1b[ks], acc2[nt], 0, 0, 0);
            }

        // epilogue2: out = relu(s^2*acc2 + s*b1), 8 x float4 per lane
        float* orow = outp + (size_t)row * 128;
#pragma unroll
        for (int nt = 0; nt < 8; ++nt) {
            floatx4 bv = *(const floatx4*)(b1 + nt * 16 + quad * 4);
            floatx4 o;
#pragma unroll
            for (int r = 0; r < 4; ++r)
                o[r] = fmaxf(s2 * acc2[nt][r] + scl * bv[r], 0.0f);
            *(floatx4*)(orow + nt * 16 + quad * 4) = o;
        }

        if (!more) break;
        s = sn;
    }
}

extern "C" void kernel_launch(void* const* d_in, const int* in_sizes, int n_in,
                              void* d_out, int out_size, void* d_ws, size_t ws_size,
                              hipStream_t stream) {
    (void)in_sizes; (void)n_in; (void)out_size; (void)ws_size;
    const float* featA = (const float*)d_in[0];
    const float* featB = (const float*)d_in[1];
    const int* dst_aa = (const int*)d_in[3];
    const int* dst_ab = (const int*)d_in[5];
    const int* dst_ba = (const int*)d_in[7];
    const float* Wr0 = (const float*)d_in[10];
    const float* br0 = (const float*)d_in[11];
    const float* Wr1 = (const float*)d_in[16];
    const float* br1 = (const float*)d_in[17];

    unsigned char* masks = (unsigned char*)d_ws;    // 3*NN bytes

    hipMemsetAsync(masks, 0, (size_t)3 * NN, stream);
    mark<<<(EE / 4 + 255) / 256, 256, 0, stream>>>(
        (const int4*)dst_aa, (const int4*)dst_ab, (const int4*)dst_ba, masks);
    fused2<<<512, 256, 0, stream>>>(featA, featB, Wr0, Wr1, br0, br1,
                                    masks, (float*)d_out);
}